// Round 13
// baseline (1045.002 us; speedup 1.0000x reference)
//
#include <hip/hip_runtime.h>
#include <hip/hip_fp16.h>

#define DS 256   // state_dim
#define DA 16    // act_dim
#define DH 30    // horizon
#define DHY 64   // hyper_dim
#define DB 64    // batch
#define DT 64    // seq len
#define TCF 8    // chunk length (fused path); 2 M buffers of TCF steps

union HV  { int4 i4; __half2 h2[4]; };
union HV2 { int2 i2; __half2 h2[2]; };
typedef _Float16 f16x8 __attribute__((ext_vector_type(8)));
typedef float f32x4 __attribute__((ext_vector_type(4)));

// ---------------- setup kernels ----------------

__global__ __launch_bounds__(64) void k_hdist(const float* __restrict__ z,
                                              const float* __restrict__ tau,
                                              const float* __restrict__ tauw,
                                              float* __restrict__ h_dist) {
  const int bb = threadIdx.x;
  if (bb >= DB) return;
  float x = tau[0];
  for (int hy = 0; hy < DHY; ++hy) x = fmaf(z[bb * DHY + hy], tauw[hy], x);
  x = fminf(fmaxf(x, -8.f), 8.f);
  const float rate = __expf(x);
  const float lr = x;
  float lp[DH];
  float lg = 0.f;
  float mx = -1e30f;
  #pragma unroll
  for (int h = 0; h < DH; ++h) {
    const float ks = (float)(h + 1);
    lg += __logf(ks);
    lp[h] = ks * lr - rate - lg;
    mx = fmaxf(mx, lp[h]);
  }
  float sum = 0.f;
  #pragma unroll
  for (int h = 0; h < DH; ++h) { lp[h] = __expf(lp[h] - mx); sum += lp[h]; }
  const float inv = 1.f / sum;
  #pragma unroll
  for (int h = 0; h < DH; ++h) h_dist[bb * DH + h] = lp[h] * inv;
}

// z fp32 -> f16 [b][hy]
__global__ __launch_bounds__(256) void k_zf16(const float* __restrict__ z,
                                              _Float16* __restrict__ zf) {
  const int i = blockIdx.x * 256 + threadIdx.x;
  if (i < DB * DHY) zf[i] = (_Float16)z[i];
}

// alpha_a = softmax(logp_u) over A. rows = T*B = 4096, 16 rows per wg.
__global__ __launch_bounds__(256) void k_alpha(const float* __restrict__ logp_u,
                                               float* __restrict__ alpha_a) {
  const int row = blockIdx.x * 16 + (threadIdx.x >> 4);
  const int k = threadIdx.x & 15;
  const float v = logp_u[(size_t)row * DA + k];
  float m = v;
  #pragma unroll
  for (int o = 8; o >= 1; o >>= 1) m = fmaxf(m, __shfl_xor(m, o, 16));
  const float e = __expf(v - m);
  float s = e;
  #pragma unroll
  for (int o = 8; o >= 1; o >>= 1) s += __shfl_xor(s, o, 16);
  alpha_a[(size_t)row * DA + k] = e / s;
}

__global__ __launch_bounds__(256) void k_zero(float* __restrict__ out_pi) {
  out_pi[blockIdx.x * 256 + threadIdx.x] = 0.f;
}

// value fp32 -> fp16 (n4 = DH*DB*DA*DS/4)
__global__ __launch_bounds__(256) void k_vconv(const float* __restrict__ v,
                                               __half* __restrict__ v16, int n4) {
  const int stride = gridDim.x * 256;
  for (int i = blockIdx.x * 256 + threadIdx.x; i < n4; i += stride) {
    const float4 f = reinterpret_cast<const float4*>(v)[i];
    reinterpret_cast<__half2*>(v16)[2 * i]     = __floats2half2_rn(f.x, f.y);
    reinterpret_cast<__half2*>(v16)[2 * i + 1] = __floats2half2_rn(f.z, f.w);
  }
}

// ---------------- k_trans via MFMA (verified R11) ----------------
__global__ __launch_bounds__(256) void k_trans(const float* __restrict__ w,
                                               const float* __restrict__ wofs,
                                               const _Float16* __restrict__ zf,
                                               __half* __restrict__ trans) {
  const int ki = blockIdx.x;
  const int t = threadIdx.x;
  const int l = t & 63;
  const int wv = t >> 6;
  __shared__ __align__(16) char smem[32 * 1024];   // A tile: 256 rows x 64 f16, swizzled

  {
    const float* wrow = wofs + (size_t)ki * (DS * DHY);
    const int q = t & 3;
    #pragma unroll
    for (int pass = 0; pass < 4; ++pass) {
      const int j = pass * 64 + (t >> 2);
      const float4* src = reinterpret_cast<const float4*>(wrow + (size_t)j * DHY + q * 16);
      const float4 f0 = src[0], f1 = src[1], f2 = src[2], f3 = src[3];
      __half2 h[8];
      h[0] = __floats2half2_rn(f0.x, f0.y); h[1] = __floats2half2_rn(f0.z, f0.w);
      h[2] = __floats2half2_rn(f1.x, f1.y); h[3] = __floats2half2_rn(f1.z, f1.w);
      h[4] = __floats2half2_rn(f2.x, f2.y); h[5] = __floats2half2_rn(f2.z, f2.w);
      h[6] = __floats2half2_rn(f3.x, f3.y); h[7] = __floats2half2_rn(f3.z, f3.w);
      const int4* hv = reinterpret_cast<const int4*>(h);
      int b0 = j * 128 + (q * 2) * 16;     b0 ^= ((j & 7) << 4);
      int b1 = j * 128 + (q * 2 + 1) * 16; b1 ^= ((j & 7) << 4);
      *reinterpret_cast<int4*>(smem + b0) = hv[0];
      *reinterpret_cast<int4*>(smem + b1) = hv[1];
    }
  }
  __syncthreads();

  const int bcol = wv * 16 + (l & 15);
  const f16x8 Bf0 = *reinterpret_cast<const f16x8*>(zf + bcol * DHY + 0  + (l >> 4) * 8);
  const f16x8 Bf1 = *reinterpret_cast<const f16x8*>(zf + bcol * DHY + 32 + (l >> 4) * 8);

  f32x4 acc[16];
  #pragma unroll
  for (int m = 0; m < 16; ++m) {
    const int row0 = m * 16 + (l >> 4) * 4;
    const float4 w4 = *reinterpret_cast<const float4*>(w + (size_t)ki * DS + row0);
    acc[m][0] = w4.x; acc[m][1] = w4.y; acc[m][2] = w4.z; acc[m][3] = w4.w;
  }
  #pragma unroll
  for (int m = 0; m < 16; ++m) {
    const int row = m * 16 + (l & 15);
    int ba = row * 128 + (l >> 4) * 16;        ba ^= ((row & 7) << 4);
    int bb = row * 128 + (4 + (l >> 4)) * 16;  bb ^= ((row & 7) << 4);
    const f16x8 a0 = *reinterpret_cast<const f16x8*>(smem + ba);
    const f16x8 a1 = *reinterpret_cast<const f16x8*>(smem + bb);
    acc[m] = __builtin_amdgcn_mfma_f32_16x16x32_f16(a0, Bf0, acc[m], 0, 0, 0);
    acc[m] = __builtin_amdgcn_mfma_f32_16x16x32_f16(a1, Bf1, acc[m], 0, 0, 0);
  }

  float ssum = 0.f;
  #pragma unroll
  for (int m = 0; m < 16; ++m) {
    acc[m][0] = __expf(acc[m][0]); acc[m][1] = __expf(acc[m][1]);
    acc[m][2] = __expf(acc[m][2]); acc[m][3] = __expf(acc[m][3]);
    ssum += (acc[m][0] + acc[m][1]) + (acc[m][2] + acc[m][3]);
  }
  ssum += __shfl_xor(ssum, 16, 64);
  ssum += __shfl_xor(ssum, 32, 64);
  const float inv = 1.f / ssum;

  __half* tb = trans + (size_t)bcol * (DA * DS * DS) + (size_t)ki * DS;
  #pragma unroll
  for (int m = 0; m < 16; ++m) {
    const int j0 = m * 16 + (l >> 4) * 4;
    union { int2 i2; __half2 h[2]; } o;
    o.h[0] = __floats2half2_rn(acc[m][0] * inv, acc[m][1] * inv);
    o.h[1] = __floats2half2_rn(acc[m][2] * inv, acc[m][3] * inv);
    *reinterpret_cast<int2*>(tb + j0) = o.i2;
  }
}

// ---------------- fused chunk kernel ----------------
// grid = 448 wgs x 1024 thr. wg-uniform branch (barriers legal):
//   wg [0,64):    scan chunk c       (reads M[c&1], written by PREVIOUS kernel)
//   wg [64,320):  mbuild chunk c+1   (writes M[(c+1)&1])
//   wg [320,448): planall chunk c-1  (reads out_b written by previous kernel)
// All dependencies cross kernel boundaries -> race-free for any dispatch order.
#define LBAR() asm volatile("s_waitcnt lgkmcnt(0)\n\ts_barrier" ::: "memory")

#define SC_ISSUE(S, T)                                                          \
  if ((T) < TCF) {                                                              \
    const __half* mb_ = Mch + (((size_t)(T) * DB + b) << 16) + jg * 8;          \
    S##0 = *reinterpret_cast<const int4*>(mb_ + (size_t)(iq + 0 * 32) * DS);    \
    S##1 = *reinterpret_cast<const int4*>(mb_ + (size_t)(iq + 1 * 32) * DS);    \
    S##2 = *reinterpret_cast<const int4*>(mb_ + (size_t)(iq + 2 * 32) * DS);    \
    S##3 = *reinterpret_cast<const int4*>(mb_ + (size_t)(iq + 3 * 32) * DS);    \
    S##4 = *reinterpret_cast<const int4*>(mb_ + (size_t)(iq + 4 * 32) * DS);    \
    S##5 = *reinterpret_cast<const int4*>(mb_ + (size_t)(iq + 5 * 32) * DS);    \
    S##6 = *reinterpret_cast<const int4*>(mb_ + (size_t)(iq + 6 * 32) * DS);    \
    S##7 = *reinterpret_cast<const int4*>(mb_ + (size_t)(iq + 7 * 32) * DS);    \
    if (tid < 64) lo_##S = *reinterpret_cast<const float4*>(                    \
        logp_o + ((size_t)(t0 + (T)) * DB + b) * DS + tid * 4);                 \
  }

#define SC_ACC1(Q, IT) {                                                 \
    const float wgt = bl[(IT) * 32 + iq];                                \
    HV u; u.i4 = (Q);                                                    \
    const float2 f0 = __half22float2(u.h2[0]);                           \
    const float2 f1 = __half22float2(u.h2[1]);                           \
    const float2 f2 = __half22float2(u.h2[2]);                           \
    const float2 f3 = __half22float2(u.h2[3]);                           \
    acc0 = fmaf(wgt, f0.x, acc0); acc1 = fmaf(wgt, f0.y, acc1);          \
    acc2 = fmaf(wgt, f1.x, acc2); acc3 = fmaf(wgt, f1.y, acc3);          \
    acc4 = fmaf(wgt, f2.x, acc4); acc5 = fmaf(wgt, f2.y, acc5);          \
    acc6 = fmaf(wgt, f3.x, acc6); acc7 = fmaf(wgt, f3.y, acc7); }

#define SC_STEP(S, T) {                                                  \
    float acc0=0.f,acc1=0.f,acc2=0.f,acc3=0.f,acc4=0.f,acc5=0.f,acc6=0.f,acc7=0.f; \
    SC_ACC1(S##0, 0) SC_ACC1(S##1, 1) SC_ACC1(S##2, 2) SC_ACC1(S##3, 3)  \
    SC_ACC1(S##4, 4) SC_ACC1(S##5, 5) SC_ACC1(S##6, 6) SC_ACC1(S##7, 7)  \
    acc0 += __shfl_xor(acc0, 32, 64); acc1 += __shfl_xor(acc1, 32, 64);  \
    acc2 += __shfl_xor(acc2, 32, 64); acc3 += __shfl_xor(acc3, 32, 64);  \
    acc4 += __shfl_xor(acc4, 32, 64); acc5 += __shfl_xor(acc5, 32, 64);  \
    acc6 += __shfl_xor(acc6, 32, 64); acc7 += __shfl_xor(acc7, 32, 64);  \
    if (lane < 32) {                                                     \
      red[w][lane][0] = acc0; red[w][lane][1] = acc1;                    \
      red[w][lane][2] = acc2; red[w][lane][3] = acc3;                    \
      red[w][lane][4] = acc4; red[w][lane][5] = acc5;                    \
      red[w][lane][6] = acc6; red[w][lane][7] = acc7;                    \
    }                                                                    \
    const float4 loC = lo_##S;   /* capture before re-issue overwrites */\
    LBAR();  /* barrier 1: red visible */                                \
    SC_ISSUE(S, (T) + 2)         /* prefetch while wave 0 works */       \
    if (tid < 64) {                                                      \
      const int jj = tid >> 1, q0 = (tid & 1) * 4;                       \
      float4 sv = {0.f, 0.f, 0.f, 0.f};                                  \
      _Pragma("unroll")                                                  \
      for (int w2 = 0; w2 < 16; ++w2) {                                  \
        const float4 r4 = *reinterpret_cast<const float4*>(&red[w2][jj][q0]); \
        sv.x += r4.x; sv.y += r4.y; sv.z += r4.z; sv.w += r4.w;          \
      }                                                                  \
      const float e0 = __expf(__logf(sv.x + 1e-6f) + loC.x);             \
      const float e1 = __expf(__logf(sv.y + 1e-6f) + loC.y);             \
      const float e2 = __expf(__logf(sv.z + 1e-6f) + loC.z);             \
      const float e3 = __expf(__logf(sv.w + 1e-6f) + loC.w);             \
      float ps = (e0 + e1) + (e2 + e3);                                  \
      ps += __shfl_xor(ps, 1, 64);  ps += __shfl_xor(ps, 2, 64);         \
      ps += __shfl_xor(ps, 4, 64);  ps += __shfl_xor(ps, 8, 64);         \
      ps += __shfl_xor(ps, 16, 64); ps += __shfl_xor(ps, 32, 64);        \
      const float inv = 1.f / ps;                                        \
      float4 p4;                                                         \
      p4.x = e0 * inv; p4.y = e1 * inv; p4.z = e2 * inv; p4.w = e3 * inv;\
      *reinterpret_cast<float4*>(&bl[tid * 4]) = p4;                     \
      *reinterpret_cast<float4*>(                                        \
          &out_b[((size_t)(t0 + (T)) * DB + b) * DS + tid * 4]) = p4;    \
    }                                                                    \
    LBAR();  /* barrier 2: bl visible */ }

__global__ __launch_bounds__(1024, 4) void k_chunk(
    const __half* __restrict__ trans,
    const float* __restrict__ alpha_a,
    const float* __restrict__ logp_o,
    const __half* __restrict__ value16,
    const float* __restrict__ h_dist,
    const float* __restrict__ b0,
    __half* __restrict__ M,             // 2 buffers of TCF*DB*DS*DS
    float* __restrict__ bl_buf,
    float* __restrict__ out_b,
    float* __restrict__ out_pi,
    int c) {
  const int wg = blockIdx.x;
  const int tid = threadIdx.x;
  const int lane = tid & 63;
  const int w = tid >> 6;   // wave 0..15

  __shared__ __align__(16) float bl[DS];
  __shared__ __align__(16) float red[16][32][12];
  __shared__ __half2 a_lds[TCF * DA];
  __shared__ __align__(16) float bl4[4][DS];
  __shared__ float api4[4][DA];

  const size_t m_half = (size_t)TCF * DB * DS * DS;

  if (wg < 64) {
    // ================= scan chunk c =================
    if (c < 0 || c >= DT / TCF) return;
    const int b = wg;
    const int t0 = c * TCF;
    const __half* Mch = M + (size_t)(c & 1) * m_half;
    const int jg = tid & 31;
    const int iq = tid >> 5;
    if (tid < DS) bl[tid] = (t0 == 0) ? b0[b * DS + tid] : bl_buf[b * DS + tid];
    __syncthreads();
    int4 A0, A1, A2, A3, A4, A5, A6, A7;
    int4 B0, B1, B2, B3, B4, B5, B6, B7;
    float4 lo_A = {0.f, 0.f, 0.f, 0.f}, lo_B = {0.f, 0.f, 0.f, 0.f};
    SC_ISSUE(A, 0)
    SC_ISSUE(B, 1)
    #pragma unroll
    for (int tt = 0; tt < TCF; tt += 2) {
      SC_STEP(A, tt)
      SC_STEP(B, tt + 1)
    }
    if (tid < DS) bl_buf[b * DS + tid] = bl[tid];
  } else if (wg < 320) {
    // ================= mbuild chunk c+1 =================
    const int cn = c + 1;
    if (cn < 0 || cn >= DT / TCF) return;
    const int wgm = wg - 64;           // 0..255
    const int b = wgm >> 2;
    const int ich = (wgm & 3) << 6;    // 64 i's per wg
    const int t0 = cn * TCF;
    __half* Mw = M + (size_t)(cn & 1) * m_half;
    if (tid < TCF * DA)
      a_lds[tid] = __float2half2_rn(alpha_a[((size_t)(t0 + (tid >> 4)) * DB + b) * DA + (tid & 15)]);
    __syncthreads();
    #pragma unroll 1
    for (int io = 0; io < 4; ++io) {
      const int i = ich + io * 16 + w;
      const __half* tp = trans + ((size_t)b * DA * DS + i) * DS + lane * 4;
      __half2 T2[32];
      #pragma unroll
      for (int k = 0; k < 16; ++k) {
        HV2 u;
        u.i2 = *reinterpret_cast<const int2*>(tp + (size_t)k * (DS * DS));
        T2[2 * k]     = u.h2[0];
        T2[2 * k + 1] = u.h2[1];
      }
      const __half2 z2 = __float2half2_rn(0.f);
      #pragma unroll
      for (int tt = 0; tt < TCF; ++tt) {
        __half2 m0 = z2, m1 = z2;
        #pragma unroll
        for (int k = 0; k < 16; ++k) {
          const __half2 ak = a_lds[tt * DA + k];
          m0 = __hfma2(ak, T2[2 * k], m0);
          m1 = __hfma2(ak, T2[2 * k + 1], m1);
        }
        HV2 o;
        o.h2[0] = m0;
        o.h2[1] = m1;
        *reinterpret_cast<int2*>(Mw + (((size_t)tt * DB + b) * DS + i) * DS + lane * 4) = o.i2;
      }
    }
  } else {
    // ================= planall chunk c-1 =================
    const int cp = c - 1;
    if (cp < 0 || cp >= DT / TCF) return;
    const int sub = tid >> 8;          // 0..3
    const int tid2 = tid & 255;
    const int pair = (wg - 320) * 4 + sub;     // 0..511
    const int b = pair >> 3;                    // b-major: value16 L2 reuse
    const int t = cp * TCF + (pair & 7);
    const int wid2 = (tid2 >> 6);      // 0..3
    bl4[sub][tid2] = out_b[((size_t)t * DB + b) * DS + tid2];
    if (tid2 < DA) api4[sub][tid2] = 0.f;
    __syncthreads();
    const int k = lane >> 2;
    const int q = lane & 3;
    for (int p = 0; p < 8; ++p) {
      const int h = p * 4 + wid2;
      if (h < DH) {
        const __half* vr = value16 + (((size_t)h * DB + b) * DA + k) * DS + q * 64;
        const float* blq = &bl4[sub][q * 64];
        float dot = 0.f;
        #pragma unroll
        for (int ii = 0; ii < 64; ii += 8) {
          HV u;
          u.i4 = *reinterpret_cast<const int4*>(vr + ii);
          const float4 c0 = *reinterpret_cast<const float4*>(blq + ii);
          const float4 c1 = *reinterpret_cast<const float4*>(blq + ii + 4);
          const float2 f0 = __half22float2(u.h2[0]);
          const float2 f1 = __half22float2(u.h2[1]);
          const float2 f2 = __half22float2(u.h2[2]);
          const float2 f3 = __half22float2(u.h2[3]);
          dot = fmaf(f0.x, c0.x, dot); dot = fmaf(f0.y, c0.y, dot);
          dot = fmaf(f1.x, c0.z, dot); dot = fmaf(f1.y, c0.w, dot);
          dot = fmaf(f2.x, c1.x, dot); dot = fmaf(f2.y, c1.y, dot);
          dot = fmaf(f3.x, c1.z, dot); dot = fmaf(f3.y, c1.w, dot);
        }
        dot += __shfl_xor(dot, 1, 64);
        dot += __shfl_xor(dot, 2, 64);
        float mk = dot;
        #pragma unroll
        for (int o = 4; o <= 32; o <<= 1) mk = fmaxf(mk, __shfl_xor(mk, o, 64));
        const float ek = __expf(dot - mk);
        float sk = ek;
        #pragma unroll
        for (int o = 4; o <= 32; o <<= 1) sk += __shfl_xor(sk, o, 64);
        if (q == 0) atomicAdd(&api4[sub][k], (ek / sk) * h_dist[b * DH + h]);
      }
    }
    __syncthreads();
    if (tid2 < DA) out_pi[((size_t)t * DB + b) * DA + tid2] = api4[sub][tid2];
  }
}

// ---------------- fallback per-step kernel (R5) for small ws ----------------
#define K_LD(I) (*reinterpret_cast<const int4*>(tb + (size_t)((I) * 64 + rb) * DS))
#define K_FMA(QV, I) {                                              \
    HV u; u.i4 = (QV);                                              \
    const float wgt = wv[(I) * 64 + rb];                            \
    const float2 f0 = __half22float2(u.h2[0]);                      \
    const float2 f1 = __half22float2(u.h2[1]);                      \
    const float2 f2 = __half22float2(u.h2[2]);                      \
    const float2 f3 = __half22float2(u.h2[3]);                      \
    acc[0] = fmaf(wgt, f0.x, acc[0]); acc[1] = fmaf(wgt, f0.y, acc[1]); \
    acc[2] = fmaf(wgt, f1.x, acc[2]); acc[3] = fmaf(wgt, f1.y, acc[3]); \
    acc[4] = fmaf(wgt, f2.x, acc[4]); acc[5] = fmaf(wgt, f2.y, acc[5]); \
    acc[6] = fmaf(wgt, f3.x, acc[6]); acc[7] = fmaf(wgt, f3.y, acc[7]); }

__global__ __launch_bounds__(256, 2) void k_step(
    const __half* __restrict__ trans, const float* __restrict__ logp_o,
    const float* __restrict__ logp_u, const __half* __restrict__ value16,
    const float* __restrict__ h_dist, const float* __restrict__ b0,
    float* __restrict__ s_buf, float* __restrict__ out_b,
    float* __restrict__ out_pi, int t) {
  const int bb = blockIdx.x & 63;
  const int jt = blockIdx.x >> 6;
  const int tid = threadIdx.x;
  const int lane = tid & 63;
  const int wid = tid >> 6;
  __shared__ __align__(16) float wv[DA * DS];
  __shared__ __align__(16) float bl[DS];
  __shared__ float aa[DA];
  __shared__ float redm[4], reds[4];
  __shared__ float red4[4][4][8];
  __shared__ float api[DA];
  if (t > 0) {
    const int tp = t - 1;
    const float sv = s_buf[(size_t)(tp & 1) * DB * DS + bb * DS + tid];
    const float l = __logf(sv + 1e-6f) + logp_o[((size_t)tp * DB + bb) * DS + tid];
    float m = l;
    #pragma unroll
    for (int o = 32; o >= 1; o >>= 1) m = fmaxf(m, __shfl_xor(m, o, 64));
    if (lane == 0) redm[wid] = m;
    __syncthreads();
    m = fmaxf(fmaxf(redm[0], redm[1]), fmaxf(redm[2], redm[3]));
    const float e = __expf(l - m);
    float v = e;
    #pragma unroll
    for (int o = 32; o >= 1; o >>= 1) v += __shfl_xor(v, o, 64);
    if (lane == 0) reds[wid] = v;
    if (tid < DA) api[tid] = 0.f;
    __syncthreads();
    const float p = e / (reds[0] + reds[1] + reds[2] + reds[3]);
    bl[tid] = p;
    if (jt == 0) out_b[((size_t)tp * DB + bb) * DS + tid] = p;
    __syncthreads();
    const int h = jt * 4 + wid;
    const int k = lane >> 2;
    const int q = lane & 3;
    if (h < DH) {
      const __half* vr = value16 + (((size_t)h * DB + bb) * DA + k) * DS + q * 64;
      const float* blq = bl + q * 64;
      float dot = 0.f;
      #pragma unroll
      for (int ii = 0; ii < 64; ii += 8) {
        HV u;
        u.i4 = *reinterpret_cast<const int4*>(vr + ii);
        const float4 c0 = *reinterpret_cast<const float4*>(blq + ii);
        const float4 c1 = *reinterpret_cast<const float4*>(blq + ii + 4);
        const float2 f0 = __half22float2(u.h2[0]);
        const float2 f1 = __half22float2(u.h2[1]);
        const float2 f2 = __half22float2(u.h2[2]);
        const float2 f3 = __half22float2(u.h2[3]);
        dot = fmaf(f0.x, c0.x, dot); dot = fmaf(f0.y, c0.y, dot);
        dot = fmaf(f1.x, c0.z, dot); dot = fmaf(f1.y, c0.w, dot);
        dot = fmaf(f2.x, c1.x, dot); dot = fmaf(f2.y, c1.y, dot);
        dot = fmaf(f3.x, c1.z, dot); dot = fmaf(f3.y, c1.w, dot);
      }
      dot += __shfl_xor(dot, 1, 64);
      dot += __shfl_xor(dot, 2, 64);
      float mk = dot;
      #pragma unroll
      for (int o = 4; o <= 32; o <<= 1) mk = fmaxf(mk, __shfl_xor(mk, o, 64));
      const float ek = __expf(dot - mk);
      float sk = ek;
      #pragma unroll
      for (int o = 4; o <= 32; o <<= 1) sk += __shfl_xor(sk, o, 64);
      if (q == 0) atomicAdd(&api[k], (ek / sk) * h_dist[bb * DH + h]);
    }
    __syncthreads();
    if (tid < DA) atomicAdd(&out_pi[((size_t)tp * DB + bb) * DA + tid], api[tid]);
  } else {
    bl[tid] = b0[bb * DS + tid];
  }
  __syncthreads();
  if (t < DT) {
    if (tid < DA) {
      const float lg = logp_u[((size_t)t * DB + bb) * DA + tid];
      float m = lg;
      #pragma unroll
      for (int o = 8; o >= 1; o >>= 1) m = fmaxf(m, __shfl_xor(m, o, 16));
      const float e = __expf(lg - m);
      float s = e;
      #pragma unroll
      for (int o = 8; o >= 1; o >>= 1) s += __shfl_xor(s, o, 16);
      aa[tid] = e / s;
    }
    __syncthreads();
    #pragma unroll
    for (int r = tid; r < DA * DS; r += 256) wv[r] = aa[r >> 8] * bl[r & 255];
    __syncthreads();
    const int jg = tid & 3;
    const int rb = tid >> 2;
    const __half* tb = trans + (size_t)bb * (DA * DS * DS) + jt * 32 + jg * 8;
    float acc[8] = {0.f, 0.f, 0.f, 0.f, 0.f, 0.f, 0.f, 0.f};
    int4 Q0 = K_LD(0), Q1 = K_LD(1), Q2 = K_LD(2), Q3 = K_LD(3);
    int4 Q4 = K_LD(4), Q5 = K_LD(5), Q6 = K_LD(6), Q7 = K_LD(7);
    #pragma unroll
    for (int it = 0; it < 56; it += 8) {
      K_FMA(Q0, it + 0); Q0 = K_LD(it + 8);
      K_FMA(Q1, it + 1); Q1 = K_LD(it + 9);
      K_FMA(Q2, it + 2); Q2 = K_LD(it + 10);
      K_FMA(Q3, it + 3); Q3 = K_LD(it + 11);
      K_FMA(Q4, it + 4); Q4 = K_LD(it + 12);
      K_FMA(Q5, it + 5); Q5 = K_LD(it + 13);
      K_FMA(Q6, it + 6); Q6 = K_LD(it + 14);
      K_FMA(Q7, it + 7); Q7 = K_LD(it + 15);
    }
    K_FMA(Q0, 56); K_FMA(Q1, 57); K_FMA(Q2, 58); K_FMA(Q3, 59);
    K_FMA(Q4, 60); K_FMA(Q5, 61); K_FMA(Q6, 62); K_FMA(Q7, 63);
    #pragma unroll
    for (int q = 0; q < 8; ++q) {
      acc[q] += __shfl_xor(acc[q], 4, 64);
      acc[q] += __shfl_xor(acc[q], 8, 64);
      acc[q] += __shfl_xor(acc[q], 16, 64);
      acc[q] += __shfl_xor(acc[q], 32, 64);
    }
    if (lane < 4) {
      #pragma unroll
      for (int q = 0; q < 8; ++q) red4[wid][lane][q] = acc[q];
    }
    __syncthreads();
    if (tid < 32) {
      const int jg2 = tid >> 3, q2 = tid & 7;
      const float s = red4[0][jg2][q2] + red4[1][jg2][q2] +
                      red4[2][jg2][q2] + red4[3][jg2][q2];
      s_buf[(size_t)(t & 1) * DB * DS + bb * DS + jt * 32 + jg2 * 8 + q2] = s;
    }
  }
}

// ---------------- launch ----------------

extern "C" void kernel_launch(void* const* d_in, const int* in_sizes, int n_in,
                              void* d_out, int out_size, void* d_ws, size_t ws_size,
                              hipStream_t stream) {
  const float* logp_o = (const float*)d_in[0];
  const float* logp_u = (const float*)d_in[1];
  const float* value  = (const float*)d_in[2];
  const float* z      = (const float*)d_in[3];
  const float* b0     = (const float*)d_in[4];
  const float* w      = (const float*)d_in[5];
  const float* wofs   = (const float*)d_in[6];
  const float* tau    = (const float*)d_in[7];
  const float* tauw   = (const float*)d_in[8];

  char* ws = (char*)d_ws;
  size_t off = 0;
  __half* trans    = (__half*)(ws + off);    off += (size_t)DB * DA * DS * DS * sizeof(__half);
  __half* value16  = (__half*)(ws + off);    off += (size_t)DH * DB * DA * DS * sizeof(__half);
  float* alpha_a   = (float*)(ws + off);     off += (size_t)DT * DB * DA * sizeof(float);
  float* s_buf     = (float*)(ws + off);     off += (size_t)2 * DB * DS * sizeof(float);
  float* bl_buf    = (float*)(ws + off);     off += (size_t)DB * DS * sizeof(float);
  _Float16* zf16   = (_Float16*)(ws + off);  off += (size_t)DB * DHY * sizeof(_Float16);
  float* h_dist    = (float*)(ws + off);     off += 8192;
  const size_t base = off;
  if (base > ws_size) return;
  __half* M = (__half*)(ws + base);
  const size_t m_half = (size_t)TCF * DB * DS * DS * sizeof(__half);  // 67 MB
  const bool fused_ok = (base + 2 * m_half) <= ws_size;

  float* out_b  = (float*)d_out;
  float* out_pi = out_b + (size_t)DT * DB * DS;

  k_hdist<<<1, 64, 0, stream>>>(z, tau, tauw, h_dist);
  k_zf16<<<16, 256, 0, stream>>>(z, zf16);
  k_vconv<<<1024, 256, 0, stream>>>(value, value16, DH * DB * DA * DS / 4);
  k_trans<<<DA * DS, 256, 0, stream>>>(w, wofs, zf16, trans);

  if (fused_ok) {
    k_alpha<<<256, 256, 0, stream>>>(logp_u, alpha_a);
    // c=-1: mbuild(0) only. c=0..7: scan(c) || mbuild(c+1) || planall(c-1). c=8: planall(7).
    for (int c = -1; c <= DT / TCF; ++c) {
      k_chunk<<<448, 1024, 0, stream>>>(trans, alpha_a, logp_o, value16, h_dist,
                                        b0, M, bl_buf, out_b, out_pi, c);
    }
  } else {
    k_zero<<<256, 256, 0, stream>>>(out_pi);
    for (int t = 0; t <= DT; ++t) {
      k_step<<<512, 256, 0, stream>>>(trans, logp_o, logp_u, value16, h_dist, b0,
                                      s_buf, out_b, out_pi, t);
    }
  }
}

// Round 14
// 596.490 us; speedup vs baseline: 1.7519x; 1.7519x over previous
//
#include <hip/hip_runtime.h>
#include <hip/hip_fp16.h>

#define DS 256   // state_dim
#define DA 16    // act_dim
#define DH 30    // horizon
#define DHY 64   // hyper_dim
#define DB 64    // batch
#define DT 64    // seq len

union HV  { int4 i4; __half2 h2[4]; };
union HV2 { int2 i2; __half2 h2[2]; };
typedef _Float16 f16x8 __attribute__((ext_vector_type(8)));
typedef float f32x4 __attribute__((ext_vector_type(4)));

// ---------------- merged setup kernel ----------------
// grid = 1297 wgs x 256thr, wg-uniform branch, no cross-branch deps:
//   wg 0:          h_dist (threads 0..63)
//   wg 1..16:      z fp32 -> f16 (4096 elems)
//   wg 17..272:    alpha_a softmax (4096 rows, 16 rows/wg)
//   wg 273..1296:  value fp32 -> fp16 (grid-stride over n4)
__global__ __launch_bounds__(256) void k_setup(const float* __restrict__ z,
                                               const float* __restrict__ tau,
                                               const float* __restrict__ tauw,
                                               const float* __restrict__ logp_u,
                                               const float* __restrict__ value,
                                               float* __restrict__ h_dist,
                                               _Float16* __restrict__ zf,
                                               float* __restrict__ alpha_a,
                                               __half* __restrict__ v16, int n4) {
  const int wg = blockIdx.x;
  if (wg == 0) {
    const int bb = threadIdx.x;
    if (bb >= DB) return;
    float x = tau[0];
    for (int hy = 0; hy < DHY; ++hy) x = fmaf(z[bb * DHY + hy], tauw[hy], x);
    x = fminf(fmaxf(x, -8.f), 8.f);
    const float rate = __expf(x);
    const float lr = x;
    float lp[DH];
    float lg = 0.f;
    float mx = -1e30f;
    #pragma unroll
    for (int h = 0; h < DH; ++h) {
      const float ks = (float)(h + 1);
      lg += __logf(ks);
      lp[h] = ks * lr - rate - lg;
      mx = fmaxf(mx, lp[h]);
    }
    float sum = 0.f;
    #pragma unroll
    for (int h = 0; h < DH; ++h) { lp[h] = __expf(lp[h] - mx); sum += lp[h]; }
    const float inv = 1.f / sum;
    #pragma unroll
    for (int h = 0; h < DH; ++h) h_dist[bb * DH + h] = lp[h] * inv;
  } else if (wg < 17) {
    const int i = (wg - 1) * 256 + threadIdx.x;
    if (i < DB * DHY) zf[i] = (_Float16)z[i];
  } else if (wg < 273) {
    const int row = (wg - 17) * 16 + (threadIdx.x >> 4);
    const int k = threadIdx.x & 15;
    const float v = logp_u[(size_t)row * DA + k];
    float m = v;
    #pragma unroll
    for (int o = 8; o >= 1; o >>= 1) m = fmaxf(m, __shfl_xor(m, o, 16));
    const float e = __expf(v - m);
    float s = e;
    #pragma unroll
    for (int o = 8; o >= 1; o >>= 1) s += __shfl_xor(s, o, 16);
    alpha_a[(size_t)row * DA + k] = e / s;
  } else {
    const int stride = 1024 * 256;
    for (int i = (wg - 273) * 256 + threadIdx.x; i < n4; i += stride) {
      const float4 f = reinterpret_cast<const float4*>(value)[i];
      reinterpret_cast<__half2*>(v16)[2 * i]     = __floats2half2_rn(f.x, f.y);
      reinterpret_cast<__half2*>(v16)[2 * i + 1] = __floats2half2_rn(f.z, f.w);
    }
  }
}

__global__ __launch_bounds__(256) void k_zero(float* __restrict__ out_pi) {
  out_pi[blockIdx.x * 256 + threadIdx.x] = 0.f;
}

// ---------------- k_trans via MFMA (verified R11) ----------------
__global__ __launch_bounds__(256) void k_trans(const float* __restrict__ w,
                                               const float* __restrict__ wofs,
                                               const _Float16* __restrict__ zf,
                                               __half* __restrict__ trans) {
  const int ki = blockIdx.x;
  const int t = threadIdx.x;
  const int l = t & 63;
  const int wv = t >> 6;
  __shared__ __align__(16) char smem[32 * 1024];   // A tile: 256 rows x 64 f16, swizzled

  {
    const float* wrow = wofs + (size_t)ki * (DS * DHY);
    const int q = t & 3;
    #pragma unroll
    for (int pass = 0; pass < 4; ++pass) {
      const int j = pass * 64 + (t >> 2);
      const float4* src = reinterpret_cast<const float4*>(wrow + (size_t)j * DHY + q * 16);
      const float4 f0 = src[0], f1 = src[1], f2 = src[2], f3 = src[3];
      __half2 h[8];
      h[0] = __floats2half2_rn(f0.x, f0.y); h[1] = __floats2half2_rn(f0.z, f0.w);
      h[2] = __floats2half2_rn(f1.x, f1.y); h[3] = __floats2half2_rn(f1.z, f1.w);
      h[4] = __floats2half2_rn(f2.x, f2.y); h[5] = __floats2half2_rn(f2.z, f2.w);
      h[6] = __floats2half2_rn(f3.x, f3.y); h[7] = __floats2half2_rn(f3.z, f3.w);
      const int4* hv = reinterpret_cast<const int4*>(h);
      int b0 = j * 128 + (q * 2) * 16;     b0 ^= ((j & 7) << 4);
      int b1 = j * 128 + (q * 2 + 1) * 16; b1 ^= ((j & 7) << 4);
      *reinterpret_cast<int4*>(smem + b0) = hv[0];
      *reinterpret_cast<int4*>(smem + b1) = hv[1];
    }
  }
  __syncthreads();

  const int bcol = wv * 16 + (l & 15);
  const f16x8 Bf0 = *reinterpret_cast<const f16x8*>(zf + bcol * DHY + 0  + (l >> 4) * 8);
  const f16x8 Bf1 = *reinterpret_cast<const f16x8*>(zf + bcol * DHY + 32 + (l >> 4) * 8);

  f32x4 acc[16];
  #pragma unroll
  for (int m = 0; m < 16; ++m) {
    const int row0 = m * 16 + (l >> 4) * 4;
    const float4 w4 = *reinterpret_cast<const float4*>(w + (size_t)ki * DS + row0);
    acc[m][0] = w4.x; acc[m][1] = w4.y; acc[m][2] = w4.z; acc[m][3] = w4.w;
  }
  #pragma unroll
  for (int m = 0; m < 16; ++m) {
    const int row = m * 16 + (l & 15);
    int ba = row * 128 + (l >> 4) * 16;        ba ^= ((row & 7) << 4);
    int bb = row * 128 + (4 + (l >> 4)) * 16;  bb ^= ((row & 7) << 4);
    const f16x8 a0 = *reinterpret_cast<const f16x8*>(smem + ba);
    const f16x8 a1 = *reinterpret_cast<const f16x8*>(smem + bb);
    acc[m] = __builtin_amdgcn_mfma_f32_16x16x32_f16(a0, Bf0, acc[m], 0, 0, 0);
    acc[m] = __builtin_amdgcn_mfma_f32_16x16x32_f16(a1, Bf1, acc[m], 0, 0, 0);
  }

  float ssum = 0.f;
  #pragma unroll
  for (int m = 0; m < 16; ++m) {
    acc[m][0] = __expf(acc[m][0]); acc[m][1] = __expf(acc[m][1]);
    acc[m][2] = __expf(acc[m][2]); acc[m][3] = __expf(acc[m][3]);
    ssum += (acc[m][0] + acc[m][1]) + (acc[m][2] + acc[m][3]);
  }
  ssum += __shfl_xor(ssum, 16, 64);
  ssum += __shfl_xor(ssum, 32, 64);
  const float inv = 1.f / ssum;

  __half* tb = trans + (size_t)bcol * (DA * DS * DS) + (size_t)ki * DS;
  #pragma unroll
  for (int m = 0; m < 16; ++m) {
    const int j0 = m * 16 + (l >> 4) * 4;
    union { int2 i2; __half2 h[2]; } o;
    o.h[0] = __floats2half2_rn(acc[m][0] * inv, acc[m][1] * inv);
    o.h[1] = __floats2half2_rn(acc[m][2] * inv, acc[m][3] * inv);
    *reinterpret_cast<int2*>(tb + j0) = o.i2;
  }
}

// ---------------- M precompute: packed fp16 (R12-verified) ----------------
__global__ __launch_bounds__(256) void k_mbuild(const __half* __restrict__ trans,
                                                const float* __restrict__ alpha_a,
                                                __half* __restrict__ Mch,
                                                int t0, int TC) {
  const int b = blockIdx.x >> 4;
  const int ich = (blockIdx.x & 15) << 4;
  const int tid = threadIdx.x;
  const int lane = tid & 63;
  const int wid = tid >> 6;
  __shared__ __half2 a_lds[16 * DA];   // TC <= 16
  for (int r = tid; r < TC * DA; r += 256)
    a_lds[r] = __float2half2_rn(alpha_a[((size_t)(t0 + (r >> 4)) * DB + b) * DA + (r & 15)]);
  __syncthreads();
  for (int io = 0; io < 4; ++io) {
    const int i = ich + io * 4 + wid;
    const __half* tp = trans + ((size_t)b * DA * DS + i) * DS + lane * 4;
    __half2 T2[32];
    #pragma unroll
    for (int k = 0; k < 16; ++k) {
      HV2 u;
      u.i2 = *reinterpret_cast<const int2*>(tp + (size_t)k * (DS * DS));
      T2[2 * k]     = u.h2[0];
      T2[2 * k + 1] = u.h2[1];
    }
    const __half2 z2 = __float2half2_rn(0.f);
    for (int tt = 0; tt < TC; ++tt) {
      __half2 m0 = z2, m1 = z2;
      #pragma unroll
      for (int k = 0; k < 16; ++k) {
        const __half2 ak = a_lds[tt * DA + k];
        m0 = __hfma2(ak, T2[2 * k], m0);
        m1 = __hfma2(ak, T2[2 * k + 1], m1);
      }
      HV2 o;
      o.h2[0] = m0;
      o.h2[1] = m1;
      *reinterpret_cast<int2*>(Mch + (((size_t)tt * DB + b) * DS + i) * DS + lane * 4) = o.i2;
    }
  }
}

// ---------------- scan chunk v3 (R12-verified): 2 barriers/step, wave-0 softmax ----------------
#define LBAR() asm volatile("s_waitcnt lgkmcnt(0)\n\ts_barrier" ::: "memory")

#define SC_ISSUE(S, T)                                                          \
  if ((T) < TC) {                                                               \
    const __half* mb_ = Mch + (((size_t)(T) * DB + b) << 16) + jg * 8;          \
    S##0 = *reinterpret_cast<const int4*>(mb_ + (size_t)(iq + 0 * 32) * DS);    \
    S##1 = *reinterpret_cast<const int4*>(mb_ + (size_t)(iq + 1 * 32) * DS);    \
    S##2 = *reinterpret_cast<const int4*>(mb_ + (size_t)(iq + 2 * 32) * DS);    \
    S##3 = *reinterpret_cast<const int4*>(mb_ + (size_t)(iq + 3 * 32) * DS);    \
    S##4 = *reinterpret_cast<const int4*>(mb_ + (size_t)(iq + 4 * 32) * DS);    \
    S##5 = *reinterpret_cast<const int4*>(mb_ + (size_t)(iq + 5 * 32) * DS);    \
    S##6 = *reinterpret_cast<const int4*>(mb_ + (size_t)(iq + 6 * 32) * DS);    \
    S##7 = *reinterpret_cast<const int4*>(mb_ + (size_t)(iq + 7 * 32) * DS);    \
    if (tid < 64) lo_##S = *reinterpret_cast<const float4*>(                    \
        logp_o + ((size_t)(t0 + (T)) * DB + b) * DS + tid * 4);                 \
  }

#define SC_ACC1(Q, IT) {                                                 \
    const float wgt = bl[(IT) * 32 + iq];                                \
    HV u; u.i4 = (Q);                                                    \
    const float2 f0 = __half22float2(u.h2[0]);                           \
    const float2 f1 = __half22float2(u.h2[1]);                           \
    const float2 f2 = __half22float2(u.h2[2]);                           \
    const float2 f3 = __half22float2(u.h2[3]);                           \
    acc0 = fmaf(wgt, f0.x, acc0); acc1 = fmaf(wgt, f0.y, acc1);          \
    acc2 = fmaf(wgt, f1.x, acc2); acc3 = fmaf(wgt, f1.y, acc3);          \
    acc4 = fmaf(wgt, f2.x, acc4); acc5 = fmaf(wgt, f2.y, acc5);          \
    acc6 = fmaf(wgt, f3.x, acc6); acc7 = fmaf(wgt, f3.y, acc7); }

#define SC_STEP(S, T) {                                                  \
    float acc0=0.f,acc1=0.f,acc2=0.f,acc3=0.f,acc4=0.f,acc5=0.f,acc6=0.f,acc7=0.f; \
    SC_ACC1(S##0, 0) SC_ACC1(S##1, 1) SC_ACC1(S##2, 2) SC_ACC1(S##3, 3)  \
    SC_ACC1(S##4, 4) SC_ACC1(S##5, 5) SC_ACC1(S##6, 6) SC_ACC1(S##7, 7)  \
    acc0 += __shfl_xor(acc0, 32, 64); acc1 += __shfl_xor(acc1, 32, 64);  \
    acc2 += __shfl_xor(acc2, 32, 64); acc3 += __shfl_xor(acc3, 32, 64);  \
    acc4 += __shfl_xor(acc4, 32, 64); acc5 += __shfl_xor(acc5, 32, 64);  \
    acc6 += __shfl_xor(acc6, 32, 64); acc7 += __shfl_xor(acc7, 32, 64);  \
    if (lane < 32) {                                                     \
      red[w][lane][0] = acc0; red[w][lane][1] = acc1;                    \
      red[w][lane][2] = acc2; red[w][lane][3] = acc3;                    \
      red[w][lane][4] = acc4; red[w][lane][5] = acc5;                    \
      red[w][lane][6] = acc6; red[w][lane][7] = acc7;                    \
    }                                                                    \
    const float4 loC = lo_##S;   /* capture before re-issue overwrites */\
    LBAR();  /* barrier 1: red visible */                                \
    SC_ISSUE(S, (T) + 2)         /* prefetch while wave 0 works */       \
    if (tid < 64) {                                                      \
      const int jj = tid >> 1, q0 = (tid & 1) * 4;                       \
      float4 sv = {0.f, 0.f, 0.f, 0.f};                                  \
      _Pragma("unroll")                                                  \
      for (int w2 = 0; w2 < 16; ++w2) {                                  \
        const float4 r4 = *reinterpret_cast<const float4*>(&red[w2][jj][q0]); \
        sv.x += r4.x; sv.y += r4.y; sv.z += r4.z; sv.w += r4.w;          \
      }                                                                  \
      const float e0 = __expf(__logf(sv.x + 1e-6f) + loC.x);             \
      const float e1 = __expf(__logf(sv.y + 1e-6f) + loC.y);             \
      const float e2 = __expf(__logf(sv.z + 1e-6f) + loC.z);             \
      const float e3 = __expf(__logf(sv.w + 1e-6f) + loC.w);             \
      float ps = (e0 + e1) + (e2 + e3);                                  \
      ps += __shfl_xor(ps, 1, 64);  ps += __shfl_xor(ps, 2, 64);         \
      ps += __shfl_xor(ps, 4, 64);  ps += __shfl_xor(ps, 8, 64);         \
      ps += __shfl_xor(ps, 16, 64); ps += __shfl_xor(ps, 32, 64);        \
      const float inv = 1.f / ps;                                        \
      float4 p4;                                                         \
      p4.x = e0 * inv; p4.y = e1 * inv; p4.z = e2 * inv; p4.w = e3 * inv;\
      *reinterpret_cast<float4*>(&bl[tid * 4]) = p4;                     \
      *reinterpret_cast<float4*>(                                        \
          &out_b[((size_t)(t0 + (T)) * DB + b) * DS + tid * 4]) = p4;    \
    }                                                                    \
    LBAR();  /* barrier 2: bl visible */ }

__global__ __launch_bounds__(1024, 4) void k_scanchunk(
    const __half* __restrict__ Mch,
    const float* __restrict__ logp_o,
    const float* __restrict__ b0,
    float* __restrict__ bl_buf,
    float* __restrict__ out_b,
    int t0, int TC) {
  const int b = blockIdx.x;
  const int tid = threadIdx.x;
  const int lane = tid & 63;
  const int w = tid >> 6;        // wave 0..15
  const int jg = tid & 31;       // j-group of 8
  const int iq = tid >> 5;       // i phase 0..31
  __shared__ __align__(16) float bl[DS];
  __shared__ __align__(16) float red[16][32][12];  // 12-wide rows: 16B-aligned float4 slots
  if (tid < DS) bl[tid] = (t0 == 0) ? b0[b * DS + tid] : bl_buf[b * DS + tid];
  __syncthreads();

  int4 A0, A1, A2, A3, A4, A5, A6, A7;
  int4 B0, B1, B2, B3, B4, B5, B6, B7;
  float4 lo_A = {0.f, 0.f, 0.f, 0.f}, lo_B = {0.f, 0.f, 0.f, 0.f};

  SC_ISSUE(A, 0)
  SC_ISSUE(B, 1)
  for (int tt = 0; tt < TC; tt += 2) {   // TC is even
    SC_STEP(A, tt)
    SC_STEP(B, tt + 1)
  }
  if (tid < DS) bl_buf[b * DS + tid] = bl[tid];
}

// ---------------- plan mega-kernel: grid = T*B wgs, B-MAJOR (L2 reuse of value16) ----------------
__global__ __launch_bounds__(256) void k_planall(const float* __restrict__ out_b,
                                                 const __half* __restrict__ value16,
                                                 const float* __restrict__ h_dist,
                                                 float* __restrict__ out_pi) {
  const int b = blockIdx.x >> 6;     // b-major: consecutive wgs share value16[.,b,.,.]
  const int t = blockIdx.x & 63;
  const int tid = threadIdx.x;
  const int lane = tid & 63;
  const int wid = tid >> 6;
  __shared__ __align__(16) float bl[DS];
  __shared__ float api[DA];
  bl[tid] = out_b[((size_t)t * DB + b) * DS + tid];
  if (tid < DA) api[tid] = 0.f;
  __syncthreads();
  const int k = lane >> 2;
  const int q = lane & 3;
  for (int p = 0; p < 8; ++p) {
    const int h = p * 4 + wid;
    if (h < DH) {
      const __half* vr = value16 + (((size_t)h * DB + b) * DA + k) * DS + q * 64;
      const float* blq = bl + q * 64;
      float dot = 0.f;
      #pragma unroll
      for (int ii = 0; ii < 64; ii += 8) {
        HV u;
        u.i4 = *reinterpret_cast<const int4*>(vr + ii);
        const float4 c0 = *reinterpret_cast<const float4*>(blq + ii);
        const float4 c1 = *reinterpret_cast<const float4*>(blq + ii + 4);
        const float2 f0 = __half22float2(u.h2[0]);
        const float2 f1 = __half22float2(u.h2[1]);
        const float2 f2 = __half22float2(u.h2[2]);
        const float2 f3 = __half22float2(u.h2[3]);
        dot = fmaf(f0.x, c0.x, dot); dot = fmaf(f0.y, c0.y, dot);
        dot = fmaf(f1.x, c0.z, dot); dot = fmaf(f1.y, c0.w, dot);
        dot = fmaf(f2.x, c1.x, dot); dot = fmaf(f2.y, c1.y, dot);
        dot = fmaf(f3.x, c1.z, dot); dot = fmaf(f3.y, c1.w, dot);
      }
      dot += __shfl_xor(dot, 1, 64);
      dot += __shfl_xor(dot, 2, 64);
      float mk = dot;
      #pragma unroll
      for (int o = 4; o <= 32; o <<= 1) mk = fmaxf(mk, __shfl_xor(mk, o, 64));
      const float ek = __expf(dot - mk);
      float sk = ek;
      #pragma unroll
      for (int o = 4; o <= 32; o <<= 1) sk += __shfl_xor(sk, o, 64);
      if (q == 0) atomicAdd(&api[k], (ek / sk) * h_dist[b * DH + h]);
    }
  }
  __syncthreads();
  if (tid < DA) out_pi[((size_t)t * DB + b) * DA + tid] = api[tid];
}

// ---------------- fallback per-step kernel (R5) for small ws ----------------
#define K_LD(I) (*reinterpret_cast<const int4*>(tb + (size_t)((I) * 64 + rb) * DS))
#define K_FMA(QV, I) {                                              \
    HV u; u.i4 = (QV);                                              \
    const float wgt = wv[(I) * 64 + rb];                            \
    const float2 f0 = __half22float2(u.h2[0]);                      \
    const float2 f1 = __half22float2(u.h2[1]);                      \
    const float2 f2 = __half22float2(u.h2[2]);                      \
    const float2 f3 = __half22float2(u.h2[3]);                      \
    acc[0] = fmaf(wgt, f0.x, acc[0]); acc[1] = fmaf(wgt, f0.y, acc[1]); \
    acc[2] = fmaf(wgt, f1.x, acc[2]); acc[3] = fmaf(wgt, f1.y, acc[3]); \
    acc[4] = fmaf(wgt, f2.x, acc[4]); acc[5] = fmaf(wgt, f2.y, acc[5]); \
    acc[6] = fmaf(wgt, f3.x, acc[6]); acc[7] = fmaf(wgt, f3.y, acc[7]); }

__global__ __launch_bounds__(256, 2) void k_step(
    const __half* __restrict__ trans, const float* __restrict__ logp_o,
    const float* __restrict__ logp_u, const __half* __restrict__ value16,
    const float* __restrict__ h_dist, const float* __restrict__ b0,
    float* __restrict__ s_buf, float* __restrict__ out_b,
    float* __restrict__ out_pi, int t) {
  const int bb = blockIdx.x & 63;
  const int jt = blockIdx.x >> 6;
  const int tid = threadIdx.x;
  const int lane = tid & 63;
  const int wid = tid >> 6;
  __shared__ __align__(16) float wv[DA * DS];
  __shared__ __align__(16) float bl[DS];
  __shared__ float aa[DA];
  __shared__ float redm[4], reds[4];
  __shared__ float red4[4][4][8];
  __shared__ float api[DA];
  if (t > 0) {
    const int tp = t - 1;
    const float sv = s_buf[(size_t)(tp & 1) * DB * DS + bb * DS + tid];
    const float l = __logf(sv + 1e-6f) + logp_o[((size_t)tp * DB + bb) * DS + tid];
    float m = l;
    #pragma unroll
    for (int o = 32; o >= 1; o >>= 1) m = fmaxf(m, __shfl_xor(m, o, 64));
    if (lane == 0) redm[wid] = m;
    __syncthreads();
    m = fmaxf(fmaxf(redm[0], redm[1]), fmaxf(redm[2], redm[3]));
    const float e = __expf(l - m);
    float v = e;
    #pragma unroll
    for (int o = 32; o >= 1; o >>= 1) v += __shfl_xor(v, o, 64);
    if (lane == 0) reds[wid] = v;
    if (tid < DA) api[tid] = 0.f;
    __syncthreads();
    const float p = e / (reds[0] + reds[1] + reds[2] + reds[3]);
    bl[tid] = p;
    if (jt == 0) out_b[((size_t)tp * DB + bb) * DS + tid] = p;
    __syncthreads();
    const int h = jt * 4 + wid;
    const int k = lane >> 2;
    const int q = lane & 3;
    if (h < DH) {
      const __half* vr = value16 + (((size_t)h * DB + bb) * DA + k) * DS + q * 64;
      const float* blq = bl + q * 64;
      float dot = 0.f;
      #pragma unroll
      for (int ii = 0; ii < 64; ii += 8) {
        HV u;
        u.i4 = *reinterpret_cast<const int4*>(vr + ii);
        const float4 c0 = *reinterpret_cast<const float4*>(blq + ii);
        const float4 c1 = *reinterpret_cast<const float4*>(blq + ii + 4);
        const float2 f0 = __half22float2(u.h2[0]);
        const float2 f1 = __half22float2(u.h2[1]);
        const float2 f2 = __half22float2(u.h2[2]);
        const float2 f3 = __half22float2(u.h2[3]);
        dot = fmaf(f0.x, c0.x, dot); dot = fmaf(f0.y, c0.y, dot);
        dot = fmaf(f1.x, c0.z, dot); dot = fmaf(f1.y, c0.w, dot);
        dot = fmaf(f2.x, c1.x, dot); dot = fmaf(f2.y, c1.y, dot);
        dot = fmaf(f3.x, c1.z, dot); dot = fmaf(f3.y, c1.w, dot);
      }
      dot += __shfl_xor(dot, 1, 64);
      dot += __shfl_xor(dot, 2, 64);
      float mk = dot;
      #pragma unroll
      for (int o = 4; o <= 32; o <<= 1) mk = fmaxf(mk, __shfl_xor(mk, o, 64));
      const float ek = __expf(dot - mk);
      float sk = ek;
      #pragma unroll
      for (int o = 4; o <= 32; o <<= 1) sk += __shfl_xor(sk, o, 64);
      if (q == 0) atomicAdd(&api[k], (ek / sk) * h_dist[bb * DH + h]);
    }
    __syncthreads();
    if (tid < DA) atomicAdd(&out_pi[((size_t)tp * DB + bb) * DA + tid], api[tid]);
  } else {
    bl[tid] = b0[bb * DS + tid];
  }
  __syncthreads();
  if (t < DT) {
    if (tid < DA) {
      const float lg = logp_u[((size_t)t * DB + bb) * DA + tid];
      float m = lg;
      #pragma unroll
      for (int o = 8; o >= 1; o >>= 1) m = fmaxf(m, __shfl_xor(m, o, 16));
      const float e = __expf(lg - m);
      float s = e;
      #pragma unroll
      for (int o = 8; o >= 1; o >>= 1) s += __shfl_xor(s, o, 16);
      aa[tid] = e / s;
    }
    __syncthreads();
    #pragma unroll
    for (int r = tid; r < DA * DS; r += 256) wv[r] = aa[r >> 8] * bl[r & 255];
    __syncthreads();
    const int jg = tid & 3;
    const int rb = tid >> 2;
    const __half* tb = trans + (size_t)bb * (DA * DS * DS) + jt * 32 + jg * 8;
    float acc[8] = {0.f, 0.f, 0.f, 0.f, 0.f, 0.f, 0.f, 0.f};
    int4 Q0 = K_LD(0), Q1 = K_LD(1), Q2 = K_LD(2), Q3 = K_LD(3);
    int4 Q4 = K_LD(4), Q5 = K_LD(5), Q6 = K_LD(6), Q7 = K_LD(7);
    #pragma unroll
    for (int it = 0; it < 56; it += 8) {
      K_FMA(Q0, it + 0); Q0 = K_LD(it + 8);
      K_FMA(Q1, it + 1); Q1 = K_LD(it + 9);
      K_FMA(Q2, it + 2); Q2 = K_LD(it + 10);
      K_FMA(Q3, it + 3); Q3 = K_LD(it + 11);
      K_FMA(Q4, it + 4); Q4 = K_LD(it + 12);
      K_FMA(Q5, it + 5); Q5 = K_LD(it + 13);
      K_FMA(Q6, it + 6); Q6 = K_LD(it + 14);
      K_FMA(Q7, it + 7); Q7 = K_LD(it + 15);
    }
    K_FMA(Q0, 56); K_FMA(Q1, 57); K_FMA(Q2, 58); K_FMA(Q3, 59);
    K_FMA(Q4, 60); K_FMA(Q5, 61); K_FMA(Q6, 62); K_FMA(Q7, 63);
    #pragma unroll
    for (int q = 0; q < 8; ++q) {
      acc[q] += __shfl_xor(acc[q], 4, 64);
      acc[q] += __shfl_xor(acc[q], 8, 64);
      acc[q] += __shfl_xor(acc[q], 16, 64);
      acc[q] += __shfl_xor(acc[q], 32, 64);
    }
    if (lane < 4) {
      #pragma unroll
      for (int q = 0; q < 8; ++q) red4[wid][lane][q] = acc[q];
    }
    __syncthreads();
    if (tid < 32) {
      const int jg2 = tid >> 3, q2 = tid & 7;
      const float s = red4[0][jg2][q2] + red4[1][jg2][q2] +
                      red4[2][jg2][q2] + red4[3][jg2][q2];
      s_buf[(size_t)(t & 1) * DB * DS + bb * DS + jt * 32 + jg2 * 8 + q2] = s;
    }
  }
}

// ---------------- launch ----------------

extern "C" void kernel_launch(void* const* d_in, const int* in_sizes, int n_in,
                              void* d_out, int out_size, void* d_ws, size_t ws_size,
                              hipStream_t stream) {
  const float* logp_o = (const float*)d_in[0];
  const float* logp_u = (const float*)d_in[1];
  const float* value  = (const float*)d_in[2];
  const float* z      = (const float*)d_in[3];
  const float* b0     = (const float*)d_in[4];
  const float* w      = (const float*)d_in[5];
  const float* wofs   = (const float*)d_in[6];
  const float* tau    = (const float*)d_in[7];
  const float* tauw   = (const float*)d_in[8];

  char* ws = (char*)d_ws;
  size_t off = 0;
  __half* trans    = (__half*)(ws + off);    off += (size_t)DB * DA * DS * DS * sizeof(__half);
  __half* value16  = (__half*)(ws + off);    off += (size_t)DH * DB * DA * DS * sizeof(__half);
  float* alpha_a   = (float*)(ws + off);     off += (size_t)DT * DB * DA * sizeof(float);
  float* s_buf     = (float*)(ws + off);     off += (size_t)2 * DB * DS * sizeof(float);
  float* bl_buf    = (float*)(ws + off);     off += (size_t)DB * DS * sizeof(float);
  _Float16* zf16   = (_Float16*)(ws + off);  off += (size_t)DB * DHY * sizeof(_Float16);
  float* h_dist    = (float*)(ws + off);     off += 8192;
  const size_t base = off;
  if (base > ws_size) return;
  __half* M = (__half*)(ws + base);
  const size_t m_per_t = (size_t)DB * DS * DS * sizeof(__half);  // 8,388,608 B
  int TC = 0;
  // CAP at 16: chunk (134 MB) must stay LLC-resident (256 MB). 32 regressed (R9: HBM refetch).
  const int cands[4] = {16, 8, 4, 2};
  for (int c = 0; c < 4; ++c)
    if (base + (size_t)cands[c] * m_per_t <= ws_size) { TC = cands[c]; break; }

  float* out_b  = (float*)d_out;
  float* out_pi = out_b + (size_t)DT * DB * DS;

  k_setup<<<1297, 256, 0, stream>>>(z, tau, tauw, logp_u, value,
                                    h_dist, zf16, alpha_a, value16,
                                    DH * DB * DA * DS / 4);
  k_trans<<<DA * DS, 256, 0, stream>>>(w, wofs, zf16, trans);

  if (TC) {
    for (int c = 0; c < DT / TC; ++c) {
      k_mbuild<<<DB * 16, 256, 0, stream>>>(trans, alpha_a, M, c * TC, TC);
      k_scanchunk<<<DB, 1024, 0, stream>>>(M, logp_o, b0, bl_buf, out_b, c * TC, TC);
    }
    k_planall<<<DT * DB, 256, 0, stream>>>(out_b, value16, h_dist, out_pi);
  } else {
    k_zero<<<256, 256, 0, stream>>>(out_pi);
    for (int t = 0; t <= DT; ++t) {
      k_step<<<512, 256, 0, stream>>>(trans, logp_o, logp_u, value16, h_dist, b0,
                                      s_buf, out_b, out_pi, t);
    }
  }
}